// Round 1
// baseline (227.425 us; speedup 1.0000x reference)
//
#include <hip/hip_runtime.h>

// Elementwise clamp: out = min(max(x, lo), hi)
// x: 33,554,432 fp32 (4194304 x 8). Pure streaming kernel:
// 128 MiB read + 128 MiB write = 268 MB -> ~42.6 us floor at 6.3 TB/s.
//
// Structure (Guideline 11/13):
//  - 2048 blocks x 256 threads, grid-stride: avoids 32k-block dispatch ramp,
//    gives the scheduler latency-hiding room.
//  - 4 independent float4 loads in flight per thread (64 B/thread/chunk).
//  - nontemporal loads+stores: 256 MB one-touch stream vs 32 MiB L2 —
//    skip cache allocation, no reuse exists.

typedef float f32x4 __attribute__((ext_vector_type(4)));

__device__ __forceinline__ f32x4 clamp4(f32x4 v, float lo, float hi) {
    // fminf(fmaxf(..)) -> compiler fuses to v_med3_f32 (clamp idiom)
    v.x = fminf(fmaxf(v.x, lo), hi);
    v.y = fminf(fmaxf(v.y, lo), hi);
    v.z = fminf(fmaxf(v.z, lo), hi);
    v.w = fminf(fmaxf(v.w, lo), hi);
    return v;
}

__global__ void __launch_bounds__(256) clamp_kernel(
    const f32x4* __restrict__ x,
    const float* __restrict__ cp,
    f32x4* __restrict__ out,
    int n4)
{
    const float lo = cp[0];
    const float hi = cp[1];
    const int stride = gridDim.x * blockDim.x;
    int i = blockIdx.x * blockDim.x + threadIdx.x;

    // Main loop: 4 independent 16B loads in flight per thread.
    for (; i + 3 * stride < n4; i += 4 * stride) {
        f32x4 v0 = __builtin_nontemporal_load(&x[i]);
        f32x4 v1 = __builtin_nontemporal_load(&x[i + stride]);
        f32x4 v2 = __builtin_nontemporal_load(&x[i + 2 * stride]);
        f32x4 v3 = __builtin_nontemporal_load(&x[i + 3 * stride]);
        v0 = clamp4(v0, lo, hi);
        v1 = clamp4(v1, lo, hi);
        v2 = clamp4(v2, lo, hi);
        v3 = clamp4(v3, lo, hi);
        __builtin_nontemporal_store(v0, &out[i]);
        __builtin_nontemporal_store(v1, &out[i + stride]);
        __builtin_nontemporal_store(v2, &out[i + 2 * stride]);
        __builtin_nontemporal_store(v3, &out[i + 3 * stride]);
    }
    // Tail (n4 = 8,388,608 divides evenly at 2048x256, but stay general).
    for (; i < n4; i += stride) {
        f32x4 v = __builtin_nontemporal_load(&x[i]);
        __builtin_nontemporal_store(clamp4(v, lo, hi), &out[i]);
    }
}

extern "C" void kernel_launch(void* const* d_in, const int* in_sizes, int n_in,
                              void* d_out, int out_size, void* d_ws, size_t ws_size,
                              hipStream_t stream)
{
    const f32x4* x = (const f32x4*)d_in[0];
    const float* cp = (const float*)d_in[1];
    f32x4* out = (f32x4*)d_out;

    const int n = in_sizes[0];          // 33,554,432 fp32 elements
    const int n4 = n / 4;               // 8,388,608 float4s (exact)

    const int block = 256;
    int grid = 2048;                    // 8 blocks/CU target, grid-stride the rest
    const int needed = (n4 + block - 1) / block;
    if (grid > needed) grid = needed;
    if (grid < 1) grid = 1;

    clamp_kernel<<<grid, block, 0, stream>>>(x, cp, out, n4);
}